// Round 1
// baseline (89.978 us; speedup 1.0000x reference)
//
#include <hip/hip_runtime.h>
#include <math.h>

// Problem constants (from reference): x is (2,2,1,80,80) f32 -> B=4 images 80x80.
#define BATCH 4
#define H 80
#define W 80
#define R 7
#define HP 74            // H - R + 1
#define L 49             // R*R
#define PAD 3            // R/2

__device__ __forceinline__ float clamp255(float v) {
    return fminf(fmaxf(v, 0.0f), 255.0f);
}

// Kernel 1: unsharp-mask preprocessing -> "division" image (integer-valued floats 0..255).
// One thread per pixel. Blur sum accumulated in double (best approximation of the
// reference's f32 reduce_window; order-dependent .5-boundary flips are rare).
__global__ void preprocess_kernel(const float* __restrict__ x, float* __restrict__ divimg) {
    int idx = blockIdx.x * blockDim.x + threadIdx.x;
    if (idx >= BATCH * H * W) return;
    int b  = idx / (H * W);
    int r  = idx % (H * W);
    int y  = r / W;
    int xc = r % W;
    const float* img = x + b * H * W;

    double s = 0.0;
    #pragma unroll
    for (int dy = -2; dy <= 2; ++dy) {
        int yy = y + dy;
        if (yy < 0 || yy >= H) continue;
        #pragma unroll
        for (int dx = -2; dx <= 2; ++dx) {
            int xx = xc + dx;
            if (xx < 0 || xx >= W) continue;
            s += (double)img[yy * W + xx];
        }
    }
    // count_include_pad=True -> always /25
    float smooth = rintf((float)(s / 25.0));
    float xv = img[y * W + xc];
    // sharp = round(clip(2.5*x - 1.25*smooth, 0, 255)); keep separate f32 roundings (no FMA contraction)
    float sharp = rintf(clamp255(__fsub_rn(__fmul_rn(2.5f, xv), __fmul_rn(1.25f, smooth))));
    // division = round(clip(sharp*255/(smooth+1e-8), 0, 255))
    float dv = rintf(clamp255(__fdiv_rn(__fmul_rn(sharp, 255.0f), __fadd_rn(smooth, 1e-8f))));
    divimg[idx] = dv;
}

// Kernel 2: KDE local entropy. One wave (64 lanes) per patch position.
// Lane i (i<49) owns patch value v_i; all-pairs via __shfl broadcast.
__global__ void entropy_kernel(const float* __restrict__ divimg, float* __restrict__ out) {
    const float INV2B2 = 0.08f;                   // 1/(2*2.5^2)
    const float NORM   = 6.266570686577501f;      // sqrt(2*pi*2.5^2), C=1
    const float EPS    = 1e-8f;

    int gtid = blockIdx.x * blockDim.x + threadIdx.x;
    int wave = gtid >> 6;
    int lane = threadIdx.x & 63;
    if (wave >= BATCH * HP * HP) return;

    int b  = wave / (HP * HP);
    int r  = wave % (HP * HP);
    int py = r / HP;
    int px = r % HP;

    float v = 0.0f;
    if (lane < L) {
        int rr = lane / R;
        int cc = lane - rr * R;
        v = divimg[b * H * W + (py + rr) * W + (px + cc)];
    }

    float acc = 0.0f;
    #pragma unroll
    for (int j = 0; j < L; ++j) {
        float vj = __shfl(v, j, 64);
        float d  = __fsub_rn(v, vj);
        float d2 = __fmul_rn(d, d);
        acc = __fadd_rn(acc, expf(__fmul_rn(-d2, INV2B2)));
    }

    float t = 0.0f;
    if (lane < L) {
        float p = __fdiv_rn(__fdiv_rn(acc, 49.0f), NORM);
        t = logf(__fadd_rn(p, EPS));
    }
    // 64-lane butterfly sum (lanes >= 49 contribute 0)
    #pragma unroll
    for (int off = 32; off; off >>= 1) {
        t += __shfl_xor(t, off, 64);
    }
    if (lane == 0) {
        out[b * H * W + (py + PAD) * W + (px + PAD)] = -__fdiv_rn(t, 49.0f);
    }
}

extern "C" void kernel_launch(void* const* d_in, const int* in_sizes, int n_in,
                              void* d_out, int out_size, void* d_ws, size_t ws_size,
                              hipStream_t stream) {
    const float* x = (const float*)d_in[0];
    float* out = (float*)d_out;
    float* divimg = (float*)d_ws;   // BATCH*H*W floats = 102400 B

    // Output border (3-wide ring) must be zero; harness poisons d_out each call.
    hipMemsetAsync(d_out, 0, (size_t)out_size * sizeof(float), stream);

    // Preprocess: 25600 pixels
    preprocess_kernel<<<(BATCH * H * W + 255) / 256, 256, 0, stream>>>(x, divimg);

    // Entropy: 4*74*74 = 21904 waves, 4 waves per 256-thread block -> 5476 blocks (exact)
    int nwaves = BATCH * HP * HP;
    int blocks = (nwaves * 64 + 255) / 256;
    entropy_kernel<<<blocks, 256, 0, stream>>>(divimg, out);
}

// Round 2
// 77.134 us; speedup vs baseline: 1.1665x; 1.1665x over previous
//
#include <hip/hip_runtime.h>
#include <math.h>

// Problem constants (from reference): x is (2,2,1,80,80) f32 -> B=4 images 80x80.
#define BATCH 4
#define H 80
#define W 80
#define R 7
#define HP 74            // H - R + 1
#define L 49             // R*R
#define PAD 3            // R/2

__device__ __forceinline__ float clamp255(float v) {
    return fminf(fmaxf(v, 0.0f), 255.0f);
}

// Kernel 1: unsharp-mask preprocessing -> "division" image (integer-valued floats 0..255).
// One thread per pixel. Blur sum accumulated in double (matches jnp f32 reduce_window
// closely enough that round() never flips; R1 measured absmax 0.0 with this).
__global__ void preprocess_kernel(const float* __restrict__ x, float* __restrict__ divimg) {
    int idx = blockIdx.x * blockDim.x + threadIdx.x;
    if (idx >= BATCH * H * W) return;
    int b  = idx / (H * W);
    int r  = idx % (H * W);
    int y  = r / W;
    int xc = r % W;
    const float* img = x + b * H * W;

    double s = 0.0;
    #pragma unroll
    for (int dy = -2; dy <= 2; ++dy) {
        int yy = y + dy;
        if (yy < 0 || yy >= H) continue;
        #pragma unroll
        for (int dx = -2; dx <= 2; ++dx) {
            int xx = xc + dx;
            if (xx < 0 || xx >= W) continue;
            s += (double)img[yy * W + xx];
        }
    }
    float smooth = rintf((float)(s / 25.0));
    float xv = img[y * W + xc];
    float sharp = rintf(clamp255(__fsub_rn(__fmul_rn(2.5f, xv), __fmul_rn(1.25f, smooth))));
    float dv = rintf(clamp255(__fdiv_rn(__fmul_rn(sharp, 255.0f), __fadd_rn(smooth, 1e-8f))));
    divimg[idx] = dv;
}

// Kernel 2: KDE local entropy. One wave (64 lanes) per OUTPUT pixel (80x80 incl. border).
// Border waves write 0 (replaces the memset dispatch). Interior: lane i<49 owns patch
// value v_i; broadcast via v_readlane (constant lane -> SGPR operand, no DS traffic);
// native v_exp_f32 via __expf.
__global__ void entropy_kernel(const float* __restrict__ divimg, float* __restrict__ out) {
    const float INV2B2 = 0.08f;                   // 1/(2*2.5^2)
    const float NORM   = 6.266570686577501f;      // sqrt(2*pi*2.5^2), C=1
    const float EPS    = 1e-8f;

    int gtid = blockIdx.x * blockDim.x + threadIdx.x;
    int wave = gtid >> 6;
    int lane = threadIdx.x & 63;
    if (wave >= BATCH * H * W) return;

    int b  = wave / (H * W);
    int r  = wave % (H * W);
    int oy = r / W;
    int ox = r % W;

    // Border ring: entropy map is padded back to HxW with zeros.
    if (oy < PAD || oy >= H - PAD || ox < PAD || ox >= W - PAD) {
        if (lane == 0) out[wave] = 0.0f;
        return;
    }
    int py = oy - PAD;   // patch origin
    int px = ox - PAD;

    float v = 0.0f;
    if (lane < L) {
        int rr = lane / R;
        int cc = lane - rr * R;
        v = divimg[b * H * W + (py + rr) * W + (px + cc)];
    }

    float acc = 0.0f;
    #pragma unroll
    for (int j = 0; j < L; ++j) {
        float vj = __uint_as_float(__builtin_amdgcn_readlane(__float_as_uint(v), j));
        float d  = v - vj;
        float d2 = d * d;
        acc += __expf(-d2 * INV2B2);   // native v_exp_f32
    }

    float t = 0.0f;
    if (lane < L) {
        float p = acc * (1.0f / (49.0f * NORM));
        t = __logf(p + EPS);           // native v_log_f32
    }
    // 64-lane butterfly sum (lanes >= 49 contribute 0)
    #pragma unroll
    for (int off = 32; off; off >>= 1) {
        t += __shfl_xor(t, off, 64);
    }
    if (lane == 0) {
        out[wave] = -t * (1.0f / 49.0f);
    }
}

extern "C" void kernel_launch(void* const* d_in, const int* in_sizes, int n_in,
                              void* d_out, int out_size, void* d_ws, size_t ws_size,
                              hipStream_t stream) {
    const float* x = (const float*)d_in[0];
    float* out = (float*)d_out;
    float* divimg = (float*)d_ws;   // BATCH*H*W floats = 102400 B

    // Preprocess: 25600 pixels
    preprocess_kernel<<<(BATCH * H * W + 255) / 256, 256, 0, stream>>>(x, divimg);

    // Entropy: one wave per output pixel, 4*80*80 = 25600 waves -> 6400 blocks of 256
    entropy_kernel<<<(BATCH * H * W * 64 + 255) / 256, 256, 0, stream>>>(divimg, out);
}

// Round 3
// 72.649 us; speedup vs baseline: 1.2385x; 1.0617x over previous
//
#include <hip/hip_runtime.h>
#include <math.h>

// Problem constants (from reference): x is (2,2,1,80,80) f32 -> B=4 images 80x80.
#define BATCH 4
#define H 80
#define W 80
#define R 7
#define HP 74            // H - R + 1
#define L 49             // R*R
#define PAD 3            // R/2

__device__ __forceinline__ float clamp255(float v) {
    return fminf(fmaxf(v, 0.0f), 255.0f);
}

// Kernel 1: unsharp-mask preprocessing -> "division" image (integer-valued floats 0..255).
// One thread per pixel. Blur sum in double (matches jnp f32 reduce_window after round;
// R1/R2 measured absmax 0.0 with this). DO NOT TOUCH — exactness verified.
__global__ void preprocess_kernel(const float* __restrict__ x, float* __restrict__ divimg) {
    int idx = blockIdx.x * blockDim.x + threadIdx.x;
    if (idx >= BATCH * H * W) return;
    int b  = idx / (H * W);
    int r  = idx % (H * W);
    int y  = r / W;
    int xc = r % W;
    const float* img = x + b * H * W;

    double s = 0.0;
    #pragma unroll
    for (int dy = -2; dy <= 2; ++dy) {
        int yy = y + dy;
        if (yy < 0 || yy >= H) continue;
        #pragma unroll
        for (int dx = -2; dx <= 2; ++dx) {
            int xx = xc + dx;
            if (xx < 0 || xx >= W) continue;
            s += (double)img[yy * W + xx];
        }
    }
    float smooth = rintf((float)(s / 25.0));
    float xv = img[y * W + xc];
    float sharp = rintf(clamp255(__fsub_rn(__fmul_rn(2.5f, xv), __fmul_rn(1.25f, smooth))));
    float dv = rintf(clamp255(__fdiv_rn(__fmul_rn(sharp, 255.0f), __fadd_rn(smooth, 1e-8f))));
    divimg[idx] = dv;
}

// Kernel 2: KDE local entropy. One wave per output pixel (80x80 incl. border ring).
// Pre-scaled values: exp(-0.08*d^2) = exp2(-((vi-vj)*k)^2), k = sqrt(0.08*log2(e)).
// Per pair: v_readlane + v_sub + v_mul(neg) + v_exp + v_add = ~12 cyc (was ~16).
__global__ void entropy_kernel(const float* __restrict__ divimg, float* __restrict__ out) {
    const float KSCALE = 0.33972871239731236f;    // sqrt(0.08 * log2(e))
    const float PSCALE = 1.0f / (49.0f * 6.266570686577501f); // 1/(49*sqrt(2*pi*b^2))
    const float EPS    = 1e-8f;
    const float LN2_49 = 0.6931471805599453f / 49.0f;

    int gtid = blockIdx.x * blockDim.x + threadIdx.x;
    int wave = gtid >> 6;
    int lane = threadIdx.x & 63;
    if (wave >= BATCH * H * W) return;

    int b  = wave / (H * W);
    int r  = wave % (H * W);
    int oy = r / W;
    int ox = r % W;

    // Border ring: entropy map is padded back to HxW with zeros.
    if (oy < PAD || oy >= H - PAD || ox < PAD || ox >= W - PAD) {
        if (lane == 0) out[wave] = 0.0f;
        return;
    }
    int py = oy - PAD;   // patch origin
    int px = ox - PAD;

    float u = 0.0f;      // pre-scaled patch value
    if (lane < L) {
        int rr = lane / R;
        int cc = lane - rr * R;
        u = divimg[b * H * W + (py + rr) * W + (px + cc)] * KSCALE;
    }

    float acc = 0.0f;
    #pragma unroll
    for (int j = 0; j < L; ++j) {
        float uj = __uint_as_float(__builtin_amdgcn_readlane(__float_as_uint(u), j));
        float s  = u - uj;
        acc += __builtin_amdgcn_exp2f(-(s * s));   // raw v_exp_f32 (base-2)
    }

    float t = 0.0f;
    if (lane < L) {
        // p + eps in one FMA, then raw v_log_f32 (base-2); ln2 factor folded into epilogue
        t = __builtin_amdgcn_logf(fmaf(acc, PSCALE, EPS));
    }
    // 64-lane butterfly sum (lanes >= 49 contribute 0)
    #pragma unroll
    for (int off = 32; off; off >>= 1) {
        t += __shfl_xor(t, off, 64);
    }
    if (lane == 0) {
        out[wave] = -t * LN2_49;    // -(ln2/49) * sum(log2(p_i))
    }
}

extern "C" void kernel_launch(void* const* d_in, const int* in_sizes, int n_in,
                              void* d_out, int out_size, void* d_ws, size_t ws_size,
                              hipStream_t stream) {
    const float* x = (const float*)d_in[0];
    float* out = (float*)d_out;
    float* divimg = (float*)d_ws;   // BATCH*H*W floats = 102400 B

    // Preprocess: 25600 pixels
    preprocess_kernel<<<(BATCH * H * W + 255) / 256, 256, 0, stream>>>(x, divimg);

    // Entropy: one wave per output pixel, 4*80*80 = 25600 waves -> 6400 blocks of 256
    entropy_kernel<<<(BATCH * H * W * 64 + 255) / 256, 256, 0, stream>>>(divimg, out);
}

// Round 4
// 66.921 us; speedup vs baseline: 1.3445x; 1.0856x over previous
//
#include <hip/hip_runtime.h>
#include <math.h>

// Problem constants (from reference): x is (2,2,1,80,80) f32 -> B=4 images 80x80.
#define BATCH 4
#define H 80
#define W 80
#define R 7
#define L 49
#define PAD 3            // R/2
#define TILES_X 40       // 2x2 output tiles per row
#define TILES 1600       // 40*40 per image

__device__ __forceinline__ float clamp255(float v) {
    return fminf(fmaxf(v, 0.0f), 255.0f);
}

// Kernel 1: unsharp-mask preprocessing -> "division" image (integer-valued floats 0..255).
// Blur sum in double (matches jnp f32 reduce_window after round; R1-R3 absmax 0.0).
// DO NOT TOUCH — exactness verified.
__global__ void preprocess_kernel(const float* __restrict__ x, float* __restrict__ divimg) {
    int idx = blockIdx.x * blockDim.x + threadIdx.x;
    if (idx >= BATCH * H * W) return;
    int b  = idx / (H * W);
    int r  = idx % (H * W);
    int y  = r / W;
    int xc = r % W;
    const float* img = x + b * H * W;

    double s = 0.0;
    #pragma unroll
    for (int dy = -2; dy <= 2; ++dy) {
        int yy = y + dy;
        if (yy < 0 || yy >= H) continue;
        #pragma unroll
        for (int dx = -2; dx <= 2; ++dx) {
            int xx = xc + dx;
            if (xx < 0 || xx >= W) continue;
            s += (double)img[yy * W + xx];
        }
    }
    float smooth = rintf((float)(s / 25.0));
    float xv = img[y * W + xc];
    float sharp = rintf(clamp255(__fsub_rn(__fmul_rn(2.5f, xv), __fmul_rn(1.25f, smooth))));
    float dv = rintf(clamp255(__fdiv_rn(__fmul_rn(sharp, 255.0f), __fadd_rn(smooth, 1e-8f))));
    divimg[idx] = dv;
}

// Kernel 2: KDE local entropy, one wave per 2x2 output tile.
// Lane (r,c) of the 8x8 grid holds the pre-scaled division value of image pixel
// (oy0-3+r, ox0-3+c) (clamped; clamped lanes only feed discarded border accs).
// The union of the four 7x7 patches is exactly the 8x8 tile = 64 lanes, so each
// distinct value-pair's exp2 is computed ONCE and added into 1-4 accumulators
// (patch membership is compile-time after full unroll).
__global__ void entropy_kernel(const float* __restrict__ divimg, float* __restrict__ out) {
    const float KSCALE = 0.33972871239731236f;    // sqrt(0.08 * log2(e))
    const float PSCALE = 1.0f / (49.0f * 6.266570686577501f); // 1/(49*sqrt(2*pi*b^2))
    const float EPS    = 1e-8f;
    const float LN2_49 = 0.6931471805599453f / 49.0f;

    int gtid = blockIdx.x * blockDim.x + threadIdx.x;
    int wave = gtid >> 6;
    int lane = threadIdx.x & 63;
    if (wave >= BATCH * TILES) return;

    int b   = wave / TILES;
    int rem = wave % TILES;
    int ty  = rem / TILES_X;
    int tx  = rem % TILES_X;
    int oy0 = 2 * ty;
    int ox0 = 2 * tx;

    // Load my value (clamped footprint coords for edge tiles)
    int lr = lane >> 3;          // row in 8x8 tile
    int lc = lane & 7;           // col in 8x8 tile
    int iy = oy0 - PAD + lr;  iy = iy < 0 ? 0 : (iy > H - 1 ? H - 1 : iy);
    int ix = ox0 - PAD + lc;  ix = ix < 0 ? 0 : (ix > W - 1 ? W - 1 : ix);
    float u = divimg[b * H * W + iy * W + ix] * KSCALE;

    // Four accumulators: patch (py,px) = lanes r in [py,py+7), c in [px,px+7)
    float a00 = 0.0f, a01 = 0.0f, a10 = 0.0f, a11 = 0.0f;
    #pragma unroll
    for (int j = 0; j < 64; ++j) {
        float uj = __uint_as_float(__builtin_amdgcn_readlane(__float_as_uint(u), j));
        float s  = u - uj;
        float e  = __builtin_amdgcn_exp2f(-(s * s));
        int rj = j >> 3, cj = j & 7;           // constant-folded per unrolled iter
        if (rj < 7 && cj < 7) a00 += e;
        if (rj < 7 && cj >= 1) a01 += e;
        if (rj >= 1 && cj < 7) a10 += e;
        if (rj >= 1 && cj >= 1) a11 += e;
    }

    // Per-pixel epilogue: lanes inside the patch contribute log2(p+eps); butterfly-sum.
    float t00 = (lr < 7 && lc < 7) ? __builtin_amdgcn_logf(fmaf(a00, PSCALE, EPS)) : 0.0f;
    float t01 = (lr < 7 && lc >= 1) ? __builtin_amdgcn_logf(fmaf(a01, PSCALE, EPS)) : 0.0f;
    float t10 = (lr >= 1 && lc < 7) ? __builtin_amdgcn_logf(fmaf(a10, PSCALE, EPS)) : 0.0f;
    float t11 = (lr >= 1 && lc >= 1) ? __builtin_amdgcn_logf(fmaf(a11, PSCALE, EPS)) : 0.0f;
    #pragma unroll
    for (int off = 32; off; off >>= 1) {
        t00 += __shfl_xor(t00, off, 64);
        t01 += __shfl_xor(t01, off, 64);
        t10 += __shfl_xor(t10, off, 64);
        t11 += __shfl_xor(t11, off, 64);
    }

    if (lane == 0) {
        float* outb = out + b * H * W;
        int oy1 = oy0 + 1, ox1 = ox0 + 1;
        bool iy0ok = (oy0 >= PAD) && (oy0 < H - PAD);
        bool iy1ok = (oy1 >= PAD) && (oy1 < H - PAD);
        bool ix0ok = (ox0 >= PAD) && (ox0 < W - PAD);
        bool ix1ok = (ox1 >= PAD) && (ox1 < W - PAD);
        float2 row0, row1;
        row0.x = (iy0ok && ix0ok) ? -t00 * LN2_49 : 0.0f;
        row0.y = (iy0ok && ix1ok) ? -t01 * LN2_49 : 0.0f;
        row1.x = (iy1ok && ix0ok) ? -t10 * LN2_49 : 0.0f;
        row1.y = (iy1ok && ix1ok) ? -t11 * LN2_49 : 0.0f;
        *(float2*)(outb + oy0 * W + ox0) = row0;   // W even, ox0 even -> 8B aligned
        *(float2*)(outb + oy1 * W + ox0) = row1;
    }
}

extern "C" void kernel_launch(void* const* d_in, const int* in_sizes, int n_in,
                              void* d_out, int out_size, void* d_ws, size_t ws_size,
                              hipStream_t stream) {
    const float* x = (const float*)d_in[0];
    float* out = (float*)d_out;
    float* divimg = (float*)d_ws;   // BATCH*H*W floats = 102400 B

    // Preprocess: 25600 pixels
    preprocess_kernel<<<(BATCH * H * W + 255) / 256, 256, 0, stream>>>(x, divimg);

    // Entropy: one wave per 2x2 tile, 4*1600 = 6400 waves -> 1600 blocks of 256
    entropy_kernel<<<(BATCH * TILES * 64 + 255) / 256, 256, 0, stream>>>(divimg, out);
}

// Round 5
// 63.158 us; speedup vs baseline: 1.4246x; 1.0596x over previous
//
#include <hip/hip_runtime.h>
#include <math.h>

// Problem constants (from reference): x is (2,2,1,80,80) f32 -> B=4 images 80x80.
#define BATCH 4
#define H 80
#define W 80
#define R 7
#define L 49
#define PAD 3            // R/2
#define TILES_X 40       // 2x2 output tiles per row
#define TILES 1600       // 40*40 per image

typedef float v2f __attribute__((ext_vector_type(2)));

__device__ __forceinline__ float clamp255(float v) {
    return fminf(fmaxf(v, 0.0f), 255.0f);
}

// Fully fused kernel: one wave per 2x2 output tile; no scratch buffer.
// Lane (lr,lc) of the 8x8 grid owns image pixel (oy0-3+lr, ox0-3+lc) (coords
// clamped at image edges; clamped lanes only feed discarded border outputs).
// Stage 1 (per lane): unsharp-mask "division" value computed directly from x
//   (5x5 zero-padded avg-pool in double — bit-identical to R1-R4's preprocess).
// Stage 2: all-pairs KDE over the 8x8 union; each pair's exp2 computed once and
//   accumulated into the 1-4 patches containing it (compile-time membership,
//   paired into v_pk_add_f32 where both halves of {a00,a01}/{a10,a11} match).
__global__ void entropy_fused_kernel(const float* __restrict__ x, float* __restrict__ out) {
    const float KSCALE = 0.33972871239731236f;    // sqrt(0.08 * log2(e))
    const float PSCALE = 1.0f / (49.0f * 6.266570686577501f); // 1/(49*sqrt(2*pi*b^2))
    const float EPS    = 1e-8f;
    const float LN2_49 = 0.6931471805599453f / 49.0f;

    int gtid = blockIdx.x * blockDim.x + threadIdx.x;
    int wave = gtid >> 6;
    int lane = threadIdx.x & 63;
    if (wave >= BATCH * TILES) return;

    int b   = wave / TILES;
    int rem = wave % TILES;
    int ty  = rem / TILES_X;
    int tx  = rem % TILES_X;
    int oy0 = 2 * ty;
    int ox0 = 2 * tx;

    int lr = lane >> 3;          // row in 8x8 tile
    int lc = lane & 7;           // col in 8x8 tile
    int iy = oy0 - PAD + lr;  iy = iy < 0 ? 0 : (iy > H - 1 ? H - 1 : iy);
    int ix = ox0 - PAD + lc;  ix = ix < 0 ? 0 : (ix > W - 1 ? W - 1 : ix);

    const float* img = x + b * H * W;

    // ---- Stage 1: division value for (iy,ix). Blur sum in double: the 25 f32
    // addends are exact in f64, so s is EXACT; s/25.0 correctly rounded; then
    // the same rintf/clamp chain as before (absmax 0.0 through R4).
    double s = 0.0;
    float xv = 0.0f;
    #pragma unroll
    for (int dy = -2; dy <= 2; ++dy) {
        int yy = iy + dy;
        bool yok = (yy >= 0) & (yy < H);
        #pragma unroll
        for (int dx = -2; dx <= 2; ++dx) {
            int xx = ix + dx;
            if (yok && xx >= 0 && xx < W) {
                float v = img[yy * W + xx];
                if (dy == 0 && dx == 0) xv = v;
                s += (double)v;
            }
        }
    }
    float smooth = rintf((float)(s / 25.0));
    float sharp  = rintf(clamp255(__fsub_rn(__fmul_rn(2.5f, xv), __fmul_rn(1.25f, smooth))));
    float dv     = rintf(clamp255(__fdiv_rn(__fmul_rn(sharp, 255.0f), __fadd_rn(smooth, 1e-8f))));
    float u      = dv * KSCALE;

    // ---- Stage 2: all-pairs exp2, shared across the 4 patches.
    v2f aA = {0.0f, 0.0f};   // {a00, a01}
    v2f aB = {0.0f, 0.0f};   // {a10, a11}
    #pragma unroll
    for (int j = 0; j < 64; ++j) {
        float uj = __uint_as_float(__builtin_amdgcn_readlane(__float_as_uint(u), j));
        float d  = u - uj;
        float e  = __builtin_amdgcn_exp2f(-(d * d));
        const int rj = j >> 3, cj = j & 7;           // compile-time after unroll
        const bool m00 = (rj < 7) && (cj < 7);
        const bool m01 = (rj < 7) && (cj >= 1);
        const bool m10 = (rj >= 1) && (cj < 7);
        const bool m11 = (rj >= 1) && (cj >= 1);
        if (m00 && m01)      { v2f ee = {e, e}; aA += ee; }
        else if (m00)        aA.x += e;
        else if (m01)        aA.y += e;
        if (m10 && m11)      { v2f ee = {e, e}; aB += ee; }
        else if (m10)        aB.x += e;
        else if (m11)        aB.y += e;
    }

    // ---- Epilogue: per-pixel log terms, butterfly sums over the wave.
    float t00 = (lr < 7 && lc < 7)  ? __builtin_amdgcn_logf(fmaf(aA.x, PSCALE, EPS)) : 0.0f;
    float t01 = (lr < 7 && lc >= 1) ? __builtin_amdgcn_logf(fmaf(aA.y, PSCALE, EPS)) : 0.0f;
    float t10 = (lr >= 1 && lc < 7) ? __builtin_amdgcn_logf(fmaf(aB.x, PSCALE, EPS)) : 0.0f;
    float t11 = (lr >= 1 && lc >= 1)? __builtin_amdgcn_logf(fmaf(aB.y, PSCALE, EPS)) : 0.0f;
    #pragma unroll
    for (int off = 32; off; off >>= 1) {
        t00 += __shfl_xor(t00, off, 64);
        t01 += __shfl_xor(t01, off, 64);
        t10 += __shfl_xor(t10, off, 64);
        t11 += __shfl_xor(t11, off, 64);
    }

    if (lane == 0) {
        float* outb = out + b * H * W;
        int oy1 = oy0 + 1, ox1 = ox0 + 1;
        bool iy0ok = (oy0 >= PAD) && (oy0 < H - PAD);
        bool iy1ok = (oy1 >= PAD) && (oy1 < H - PAD);
        bool ix0ok = (ox0 >= PAD) && (ox0 < W - PAD);
        bool ix1ok = (ox1 >= PAD) && (ox1 < W - PAD);
        float2 row0, row1;
        row0.x = (iy0ok && ix0ok) ? -t00 * LN2_49 : 0.0f;
        row0.y = (iy0ok && ix1ok) ? -t01 * LN2_49 : 0.0f;
        row1.x = (iy1ok && ix0ok) ? -t10 * LN2_49 : 0.0f;
        row1.y = (iy1ok && ix1ok) ? -t11 * LN2_49 : 0.0f;
        *(float2*)(outb + oy0 * W + ox0) = row0;   // W even, ox0 even -> 8B aligned
        *(float2*)(outb + oy1 * W + ox0) = row1;
    }
}

extern "C" void kernel_launch(void* const* d_in, const int* in_sizes, int n_in,
                              void* d_out, int out_size, void* d_ws, size_t ws_size,
                              hipStream_t stream) {
    const float* x = (const float*)d_in[0];
    float* out = (float*)d_out;
    (void)d_ws; (void)ws_size;   // no scratch: fully fused

    // One wave per 2x2 tile: 4*1600 = 6400 waves -> 1600 blocks of 256
    entropy_fused_kernel<<<(BATCH * TILES * 64 + 255) / 256, 256, 0, stream>>>(x, out);
}